// Round 3
// baseline (122.303 us; speedup 1.0000x reference)
//
#include <hip/hip_runtime.h>

// Problem constants
#define IMG_H 512
#define IMG_W 512
#define NKH 32
#define NKW 32
#define NK (NKH * NKW)   // 1024 windows
#define BATCH 64
#define NT 33            // 16x16 tiles per dim of 528x528 padded image

// Block = one 16x16 tile, all 64 batches. 256 threads (4 waves).
// Stage: LDS xt[kc][col] (float4), kc = r*4 + c4 = pixel chunk (0..63),
//        col = (b + kc) & 63  (rotation swizzle -> conflict-free both sides).
// Compute: wave = quadrant q (0..3), lane = batch b. Each thread computes the
// FULL 256-elem quadrant dot from LDS + wave-uniform weights (s_load). No
// cross-lane reduction at all. Partial[q][n][b] written exactly once
// (tile<->(window,quadrant) bijective), coalesced in b.
__global__ __launch_bounds__(256)
void bslc_tile_kernel(const float* __restrict__ x,
                      const float* __restrict__ w,
                      float* __restrict__ partial)
{
    __shared__ float4 xt[64][64];   // 64 KiB
    const int tc = blockIdx.x;      // 0..32
    const int tr = blockIdx.y;      // 0..32
    const int t  = threadIdx.x;
    const int lane = t & 63;
    const int wv   = t >> 6;

    // ---------------- stage ----------------
    // This thread's pixel chunk = lane: r = lane>>2 (tile row), c4 = lane&3.
    const int kc = lane;
    const int r  = kc >> 2;
    const int c4 = kc & 3;
    const int rimg = tr * 16 - 8 + r;
    const int cimg = tc * 16 - 8 + c4 * 4;
    const bool interior = (tr >= 1) & (tr <= 31) & (tc >= 1) & (tc <= 31);
    const size_t xoff = (size_t)rimg * IMG_W + cimg;
    const int col = (0 + kc) & 63;  // b added per-iter below

    if (interior) {
#pragma unroll
        for (int i = 0; i < 16; ++i) {
            const int b = wv + 4 * i;              // uniform within wave
            const float4 xv = *reinterpret_cast<const float4*>(
                x + (size_t)b * (IMG_H * IMG_W) + xoff);
            xt[kc][(b + kc) & 63] = xv;
        }
    } else {
#pragma unroll
        for (int i = 0; i < 16; ++i) {
            const int b = wv + 4 * i;
            float4 xv = make_float4(0.f, 0.f, 0.f, 0.f);
            if (rimg >= 0 && rimg < IMG_H) {
                const float* xb = x + (size_t)b * (IMG_H * IMG_W)
                                + (size_t)rimg * IMG_W;
#pragma unroll
                for (int e = 0; e < 4; ++e) {
                    const int c = cimg + e;
                    if (c >= 0 && c < IMG_W) (&xv.x)[e] = xb[c];
                }
            }
            xt[kc][(b + kc) & 63] = xv;
        }
    }
    (void)col;
    __syncthreads();

    // ---------------- compute ----------------
    const int q  = __builtin_amdgcn_readfirstlane(wv);  // force SGPR -> s_load weights
    const int qr = q >> 1, qc = q & 1;
    const int nr = tr - qr, nc = tc - qc;
    if (nr >= 0 && nr < NKH && nc >= 0 && nc < NKW) {
        const int n = nr * NKW + nc;
        // Weight base for this quadrant: rows qr*16+r (r=0..15), cols qc*16..+15.
        const float* wq = w + (size_t)n * 1024 + (size_t)(qr * 16) * 32 + qc * 16;
        const int b = lane;

        float s0 = 0.f, s1 = 0.f, s2 = 0.f, s3 = 0.f;
#pragma unroll
        for (int kk = 0; kk < 64; ++kk) {
            const float4 xv = xt[kk][(b + kk) & 63];
            const float4 wv4 = *reinterpret_cast<const float4*>(
                wq + (kk >> 2) * 32 + (kk & 3) * 4);   // uniform -> s_load
            s0 = fmaf(xv.x, wv4.x, s0);
            s1 = fmaf(xv.y, wv4.y, s1);
            s2 = fmaf(xv.z, wv4.z, s2);
            s3 = fmaf(xv.w, wv4.w, s3);
        }
        partial[((size_t)q * NK + n) * 64 + b] = (s0 + s1) + (s2 + s3);
    }
}

// out[b,n] = bias[n] + sum_q partial[q][n][b]
__global__ __launch_bounds__(256)
void bslc_reduce_kernel(const float* __restrict__ partial,
                        const float* __restrict__ bias,
                        float* __restrict__ out)
{
    const int g = blockIdx.x * 256 + threadIdx.x;  // 0..65535
    const int n = g >> 6;                          // uniform per wave
    const int b = g & 63;
    float s = bias[n];
#pragma unroll
    for (int q = 0; q < 4; ++q)
        s += partial[((size_t)q * NK + n) * 64 + b];
    out[(size_t)b * NK + n] = s;
}

extern "C" void kernel_launch(void* const* d_in, const int* in_sizes, int n_in,
                              void* d_out, int out_size, void* d_ws, size_t ws_size,
                              hipStream_t stream) {
    const float* x    = (const float*)d_in[0];  // (64,1,512,512) fp32
    const float* wgt  = (const float*)d_in[1];  // (1024,1024) fp32
    const float* bias = (const float*)d_in[2];  // (1024,) fp32
    float* out        = (float*)d_out;          // (64,32,32) fp32
    float* partial    = (float*)d_ws;           // 4*1024*64 floats = 1 MiB

    dim3 grid1(NT, NT);
    bslc_tile_kernel<<<grid1, 256, 0, stream>>>(x, wgt, partial);

    dim3 grid2((BATCH * NK) / 256);
    bslc_reduce_kernel<<<grid2, 256, 0, stream>>>(partial, bias, out);
}